// Round 8
// baseline (224.465 us; speedup 1.0000x reference)
//
#include <hip/hip_runtime.h>

typedef int v4i  __attribute__((ext_vector_type(4)));
typedef int v16i __attribute__((ext_vector_type(16)));

#define QMAX 127.0f

// ---- workspace layout ----
// xq  : int8 padded, swizzled [16][66][66 px][5 c5][4 slots][16]
//       PAIR swizzle (round-8): slot s holds logical ci-chunk s ^ key,
//       key = ((col>>1)&1)<<1  -> 32B chunk-PAIRS alternate 64B halves
//       every 2 columns; any 4 consecutive cols sweep a full 128B bank
//       window -> conflict-free 32x32x32 B-fragment ds_read_b128.
// wq2 : int8 fragment-order for 32x32x32 MFMA: [9 p][5 c5][2 ks][10 cot][64 lane][16]
//       lane holds co = cot*32 + (lane&31), ci = c5*64 + ks*32 + (lane>>5)*16 + j
// bi  : float [320]
#define XQ_BYTES 22302720
#define WQ_BYTES 921600

__device__ __forceinline__ float clampf(float v, float lo, float hi) {
    return fminf(fmaxf(v, lo), hi);
}

// Bit-exact fast round(v/step): reciprocal multiply, exact-division fallback
// only near half-integer boundaries (trigger ~7e-4; 50x error margin).
__device__ __forceinline__ float qround(float v, float step, float inv) {
    float t = v * inv;
    float r = rintf(t);
    float d = fabsf(t - r);
    if (fabsf(d - 0.5f) < fabsf(t) * 1e-5f + 1e-5f)
        r = rintf(v / step);
    return r;
}

__device__ __forceinline__ void gload_lds16(const char* g, char* l) {
    __builtin_amdgcn_global_load_lds(
        (const __attribute__((address_space(1))) void*)g,
        (__attribute__((address_space(3))) void*)l, 16, 0, 0);
}

__device__ __forceinline__ v16i mfma32_i8(v4i a, v4i b, v16i c) {
    return __builtin_amdgcn_mfma_i32_32x32x32_i8(a, b, c, 0, 0, 0);
}

// ---------------------------------------------------------------------------
// Fused producer kernel:
//   blocks [0,1024)    : x quantize (block = (h,b)), long pole -> first
//   blocks [1024,1124) : wq2 quantize into 32x32x32 fragment order
//   blocks [1124,1449) : xq halo zeroing
//   block  1449        : bias requant
// ---------------------------------------------------------------------------
__global__ __launch_bounds__(256) void fused_prep_kernel(
    const float* __restrict__ x, const float* __restrict__ w,
    const float* __restrict__ bias,
    const float* __restrict__ step_x_p, const float* __restrict__ step_w_p,
    const float* __restrict__ step_b_p, const float* __restrict__ shift_p,
    char* __restrict__ xq, char* __restrict__ wq2, float* __restrict__ bi)
{
    // x-quant uses F as [64][65]; wq uses F as [32][289] (36,992 B)
    __shared__ float F[32 * 289];
    const int bid = blockIdx.x;
    const int t = threadIdx.x;

    if (bid < 1024) {
        // ---- x quantize: one block per (h,b); writes row h+1 interior ----
        const int h = bid & 63;
        const int b = bid >> 6;
        const float step = *step_x_p;
        const float inv  = 1.0f / step;
        const int wcol = t >> 2;       // output col-1 (0..63)
        const int cg   = t & 3;        // logical 16-ci chunk within c5
        v4i vals[5];

        for (int c5 = 0; c5 < 5; ++c5) {
            {
                const int r = t >> 4, c = (t & 15) * 4;
                const float* src = x + (((size_t)(b * 320 + c5 * 64) * 64 + h) * 64);
#pragma unroll
                for (int i = 0; i < 4; ++i) {
                    const int row = r + i * 16;
                    *(float4*)&F[row * 65 + c] =
                        *(const float4*)(src + (size_t)row * 4096 + c);
                }
            }
            __syncthreads();
            int dws[4];
#pragma unroll
            for (int j = 0; j < 4; ++j) {
                int word = 0;
#pragma unroll
                for (int k = 0; k < 4; ++k) {
                    float v = F[(cg * 16 + j * 4 + k) * 65 + wcol];
                    int xi = (int)clampf(qround(v, step, inv), -QMAX, QMAX);
                    word |= (xi & 0xFF) << (8 * k);
                }
                dws[j] = word;
            }
            vals[c5] = (v4i){dws[0], dws[1], dws[2], dws[3]};
            __syncthreads();
        }

        const int col = wcol + 1;
        const int key = ((col >> 1) & 1) << 1;    // round-8 pair swizzle
        char* base = xq + ((size_t)(b * 66 + (h + 1)) * 66 + col) * 320;
#pragma unroll
        for (int c5 = 0; c5 < 5; ++c5)
            *(v4i*)(base + c5 * 64 + (((cg ^ key)) << 4)) = vals[c5];

    } else if (bid < 1124) {
        // ---- weight quantize into 32x32x32 fragment order ----
        // block = (cot, c5, ks): stage 32 co x 32 ci x 9 p floats, then emit
        // one coalesced 1024B block per p.
        const int blk = bid - 1024;      // 0..99
        const int cot = blk / 10;        // 0..9  (32-co tile)
        const int rem = blk - cot * 10;
        const int c5  = rem >> 1;        // 0..4
        const int ks  = rem & 1;         // 0..1  (32-ci half of c5)
        const float step = *step_w_p;
        const float inv  = 1.0f / step;

        for (int idx = t; idx < 2304; idx += 256) {
            const int co_l = idx / 72;
            const int m4   = idx - co_l * 72;
            const float4 v = *(const float4*)(
                w + (size_t)(cot * 32 + co_l) * 2880 + c5 * 576 + ks * 288 + m4 * 4);
            float* dst = &F[co_l * 289 + m4 * 4];
            dst[0] = v.x; dst[1] = v.y; dst[2] = v.z; dst[3] = v.w;
        }
        __syncthreads();

        // thread t writes bytes [t*4, t*4+4) of each p's 1024B block:
        // lane = t>>2, j0 = (t&3)*4; co_l = lane&31; ci_l = (lane>>5)*16+j0+k
        const int co_l = (t >> 2) & 31;
        const int cib  = (t >> 7) * 16 + (t & 3) * 4;
        char* dst = wq2 + (size_t)(c5 * 20 + ks * 10 + cot) * 1024 + t * 4;
#pragma unroll
        for (int p = 0; p < 9; ++p) {
            int word = 0;
#pragma unroll
            for (int k = 0; k < 4; ++k) {
                float v = F[co_l * 289 + (cib + k) * 9 + p];
                int q = (int)clampf(qround(v, step, inv), -QMAX, QMAX);
                word |= (q & 0xFF) << (8 * k);
            }
            *(int*)(dst + (size_t)p * 102400) = word;
        }
    } else if (bid < 1449) {
        // ---- halo zeroing (slot-agnostic: all zeros) ----
        int tid = (bid - 1124) * 256 + t;
        if (tid < 83200) {
            int b = tid / 5200;
            int r = tid - b * 5200;
            int px = r / 20;
            int ck = (r - px * 20) * 16;
            int row, col;
            if (px < 66)       { row = 0;  col = px; }
            else if (px < 132) { row = 65; col = px - 66; }
            else { int e = px - 132; row = 1 + (e >> 1); col = (e & 1) * 65; }
            size_t off = ((size_t)(b * 66 + row) * 66 + col) * 320 + ck;
            v4i z = {0, 0, 0, 0};
            *(v4i*)&xq[off] = z;
        }
    } else {
        // ---- bias requant ----
        const float step_b = *step_b_p;
        const float xs = 1.0f / *step_x_p;
        const float ws = 1.0f / *step_w_p;
        const float shift = *shift_p;
#pragma unroll
        for (int co = t; co < 320; co += 256) {
            float b_deq = clampf(rintf(bias[co] / step_b), -QMAX, QMAX) * step_b;
            float v = ((b_deq * shift) * xs) * ws;
            bi[co] = clampf(rintf(v), -QMAX, QMAX);
        }
    }
}

// ---------------------------------------------------------------------------
// Implicit-GEMM conv — v_mfma_i32_32x32x32_i8 (round-8: pair-swizzle fix).
// Round-4 structure preserved (grid 1280, XCD remap, dbuf B staging,
// A distance-1 dbuf, 3 waves/SIMD). 8 x 32x32x32 per p: half the MFMA
// instructions of 16x16x64, ceiling 4404 vs 3944 TOPS.
// ROUND-7 LESSON: the (col>>1)&3 chunk swizzle leaves 32B holes for 32x32
// B-fragments (32 cols x 2 chunks) -> exactly +4 cy/ds_read_b128
// (SQ_LDS_BANK_CONFLICT 3.69M). Pair swizzle key=((col>>1)&1)<<1 makes any
// 4 consecutive cols sweep a full 128B bank window -> conflict-free.
// ROUND-3 LESSON: no ptile pairing. ROUND-5: no small-tile retile.
// ROUND-6: no distance-2 prefetch.
// ---------------------------------------------------------------------------
__global__ __launch_bounds__(256, 3) void conv_mfma_kernel(
    const char* __restrict__ xq, const char* __restrict__ wq2,
    const float* __restrict__ bi, const float* __restrict__ shift_p,
    float* __restrict__ out)
{
    __shared__ __attribute__((aligned(16))) char B_lds[2][25344]; // 6 rows x 66 x 64

    const int t  = threadIdx.x;
    const int id = blockIdx.x;           // 0..1279
    // id = (ptile&7) + 8*bx + 40*(ptile>>3)  -- invert:
    const int g  = id / 40;
    const int r  = id - g * 40;
    const int bx = r >> 3;               // co tile 0..4 (64 co each)
    const int ptile = (g << 3) | (r & 7);

    const int co0 = bx * 64;
    const int b  = ptile >> 4;
    const int h0 = (ptile & 15) * 4;

    const int wave = t >> 6, lane = t & 63;
    const int l31 = lane & 31, hi = lane >> 5;

    const char* xbase = xq + ((size_t)(b * 66 + h0) * 66) * 320;

    v16i acc[2][2] = {};   // [ct (32-co tile)][h (32-px half)]

    // prologue: stage c5=0 into buffer 0
    for (int c = t; c < 1584; c += 256) {
        const char* gp = xbase + (c >> 2) * 320 + ((c & 3) << 4);
        gload_lds16(gp, &B_lds[0][(c - lane) * 16]);
    }
    __syncthreads();

    for (int c5 = 0; c5 < 5; ++c5) {
        // issue next stage's DMA first (other buffer; drained by the barrier
        // AFTER this c5's compute -> fully overlapped)
        if (c5 < 4) {
            const int ci0 = (c5 + 1) * 64;
            char* dst = B_lds[(c5 + 1) & 1];
            for (int c = t; c < 1584; c += 256) {
                const char* gp = xbase + (c >> 2) * 320 + ci0 + ((c & 3) << 4);
                gload_lds16(gp, &dst[(c - lane) * 16]);
            }
        }

        const char* Bc = B_lds[c5 & 1];
        const char* wp = wq2 + (c5 * 20 + bx * 2) * 1024 + lane * 16;

        // A distance-1 double-buffer: [buf][ct][ks]
        v4i areg[2][2][2];
#pragma unroll
        for (int ct = 0; ct < 2; ++ct)
#pragma unroll
            for (int ks = 0; ks < 2; ++ks)
                areg[0][ct][ks] = *(const v4i*)(wp + ks * 10240 + ct * 1024);

#pragma unroll
        for (int p = 0; p < 9; ++p) {
            const int dh = p / 3, dw = p - dh * 3;
            if (p < 8) {
#pragma unroll
                for (int ct = 0; ct < 2; ++ct)
#pragma unroll
                    for (int ks = 0; ks < 2; ++ks)
                        areg[(p + 1) & 1][ct][ks] = *(const v4i*)(
                            wp + (p + 1) * 102400 + ks * 10240 + ct * 1024);
            }
            const int prow = wave + dh;
            v4i bf[2][2];  // [h][ks]
#pragma unroll
            for (int h = 0; h < 2; ++h) {
                const int col = h * 32 + l31 + dw;
                const int p2  = (col >> 1) & 1;       // pair-swizzle key>>1
                const int base = (prow * 66 + col) * 64 + (hi << 4);
#pragma unroll
                for (int ks = 0; ks < 2; ++ks)
                    bf[h][ks] = *(const v4i*)&Bc[base + ((ks ^ p2) << 5)];
            }
            __builtin_amdgcn_s_setprio(1);
#pragma unroll
            for (int ks = 0; ks < 2; ++ks)      // ks outer: acc-reuse dist 4
#pragma unroll
                for (int h = 0; h < 2; ++h)
#pragma unroll
                    for (int ct = 0; ct < 2; ++ct)
                        acc[ct][h] = mfma32_i8(areg[p & 1][ct][ks], bf[h][ks],
                                               acc[ct][h]);
            __builtin_amdgcn_s_setprio(0);
        }
        __syncthreads();
    }

    // epilogue: y_shift = clip(rint(y*shift)); out = clip(y_shift + b_int8)
    // C/D 32x32: col = lane&31 (px), row = (reg&3) + 8*(reg>>2) + 4*hi (co)
    const float shift = *shift_p;
    const int h = h0 + wave;
#pragma unroll
    for (int ct = 0; ct < 2; ++ct) {
#pragma unroll
        for (int reg = 0; reg < 16; ++reg) {
            const int row = (reg & 3) + 8 * (reg >> 2) + 4 * hi;
            const int co = co0 + ct * 32 + row;
            const float bv = bi[co];
            float* orow = out + (((size_t)(b * 320 + co) * 64) + h) * 64;
#pragma unroll
            for (int hh = 0; hh < 2; ++hh) {
                float y  = (float)acc[ct][hh][reg];
                float ys = clampf(rintf(y * shift), -QMAX, QMAX);
                orow[hh * 32 + l31] = clampf(ys + bv, -QMAX, QMAX);
            }
        }
    }
}

extern "C" void kernel_launch(void* const* d_in, const int* in_sizes, int n_in,
                              void* d_out, int out_size, void* d_ws, size_t ws_size,
                              hipStream_t stream) {
    const float* x      = (const float*)d_in[0];
    const float* w      = (const float*)d_in[1];
    const float* bias   = (const float*)d_in[2];
    const float* step_x = (const float*)d_in[3];
    const float* step_w = (const float*)d_in[4];
    const float* step_b = (const float*)d_in[5];
    const float* shift  = (const float*)d_in[6];
    float* out = (float*)d_out;

    char*  xq  = (char*)d_ws;
    char*  wq2 = xq + XQ_BYTES;
    float* bi  = (float*)(wq2 + WQ_BYTES);

    fused_prep_kernel<<<1450, 256, 0, stream>>>(x, w, bias, step_x, step_w,
                                                step_b, shift, xq, wq2, bi);
    conv_mfma_kernel<<<1280, 256, 0, stream>>>(xq, wq2, bi, shift, out);
}

// Round 9
// 222.457 us; speedup vs baseline: 1.0090x; 1.0090x over previous
//
#include <hip/hip_runtime.h>

typedef int v4i  __attribute__((ext_vector_type(4)));
typedef int v16i __attribute__((ext_vector_type(16)));

#define QMAX 127.0f

// ---- workspace layout ----
// xq  : int8 padded [16 b][66 row][5 c5][2 ks][66 col][2 hi][16B]
//       (ks-SPLIT layout, round-9: no swizzle. chunk (ks,hi) holds
//        ci_local = ks*32 + hi*16 + 0..15. For a fixed (h,ks) conv
//        B-read, the wave's 64 lanes cover one contiguous 1024B LDS
//        region -> the empirically-proven 0-conflict pattern.)
// wq2 : int8 fragment-order for 32x32x32 MFMA: [9 p][5 c5][2 ks][10 cot][64 lane][16]
//       lane holds co = cot*32 + (lane&31), ci = c5*64 + ks*32 + (lane>>5)*16 + j
// bi  : float [320]
#define XQ_BYTES 22302720
#define WQ_BYTES 921600

__device__ __forceinline__ float clampf(float v, float lo, float hi) {
    return fminf(fmaxf(v, lo), hi);
}

// Bit-exact fast round(v/step): reciprocal multiply, exact-division fallback
// only near half-integer boundaries (trigger ~7e-4; 50x error margin).
__device__ __forceinline__ float qround(float v, float step, float inv) {
    float t = v * inv;
    float r = rintf(t);
    float d = fabsf(t - r);
    if (fabsf(d - 0.5f) < fabsf(t) * 1e-5f + 1e-5f)
        r = rintf(v / step);
    return r;
}

__device__ __forceinline__ void gload_lds16(const char* g, char* l) {
    __builtin_amdgcn_global_load_lds(
        (const __attribute__((address_space(1))) void*)g,
        (__attribute__((address_space(3))) void*)l, 16, 0, 0);
}

__device__ __forceinline__ v16i mfma32_i8(v4i a, v4i b, v16i c) {
    return __builtin_amdgcn_mfma_i32_32x32x32_i8(a, b, c, 0, 0, 0);
}

// ---------------------------------------------------------------------------
// Fused producer kernel:
//   blocks [0,1024)    : x quantize (block = (h,b)), long pole -> first
//   blocks [1024,1124) : wq2 quantize into 32x32x32 fragment order
//   blocks [1124,1449) : xq halo zeroing
//   block  1449        : bias requant
// ---------------------------------------------------------------------------
__global__ __launch_bounds__(256) void fused_prep_kernel(
    const float* __restrict__ x, const float* __restrict__ w,
    const float* __restrict__ bias,
    const float* __restrict__ step_x_p, const float* __restrict__ step_w_p,
    const float* __restrict__ step_b_p, const float* __restrict__ shift_p,
    char* __restrict__ xq, char* __restrict__ wq2, float* __restrict__ bi)
{
    // x-quant uses F as [64][65]; wq uses F as [32][289] (36,992 B)
    __shared__ float F[32 * 289];
    const int bid = blockIdx.x;
    const int t = threadIdx.x;

    if (bid < 1024) {
        // ---- x quantize: one block per (h,b); writes row h+1 interior ----
        const int h = bid & 63;
        const int b = bid >> 6;
        const float step = *step_x_p;
        const float inv  = 1.0f / step;
        const int wcol = t >> 2;       // output col-1 (0..63)
        const int cg   = t & 3;        // 16-ci chunk within c5 = (ks<<1)|hi
        v4i vals[5];

        for (int c5 = 0; c5 < 5; ++c5) {
            {
                const int r = t >> 4, c = (t & 15) * 4;
                const float* src = x + (((size_t)(b * 320 + c5 * 64) * 64 + h) * 64);
#pragma unroll
                for (int i = 0; i < 4; ++i) {
                    const int row = r + i * 16;
                    *(float4*)&F[row * 65 + c] =
                        *(const float4*)(src + (size_t)row * 4096 + c);
                }
            }
            __syncthreads();
            int dws[4];
#pragma unroll
            for (int j = 0; j < 4; ++j) {
                int word = 0;
#pragma unroll
                for (int k = 0; k < 4; ++k) {
                    float v = F[(cg * 16 + j * 4 + k) * 65 + wcol];
                    int xi = (int)clampf(qround(v, step, inv), -QMAX, QMAX);
                    word |= (xi & 0xFF) << (8 * k);
                }
                dws[j] = word;
            }
            vals[c5] = (v4i){dws[0], dws[1], dws[2], dws[3]};
            __syncthreads();
        }

        // ks-split layout: [c5][ks][col][hi][16]; ks = cg>>1, hi = cg&1.
        const int col = wcol + 1;
        char* base = xq + ((size_t)(b * 66 + (h + 1))) * 21120
                   + (cg >> 1) * 2112 + col * 32 + (cg & 1) * 16;
#pragma unroll
        for (int c5 = 0; c5 < 5; ++c5)
            *(v4i*)(base + c5 * 4224) = vals[c5];

    } else if (bid < 1124) {
        // ---- weight quantize into 32x32x32 fragment order ----
        // block = (cot, c5, ks): stage 32 co x 32 ci x 9 p floats, then emit
        // one coalesced 1024B block per p.
        const int blk = bid - 1024;      // 0..99
        const int cot = blk / 10;        // 0..9  (32-co tile)
        const int rem = blk - cot * 10;
        const int c5  = rem >> 1;        // 0..4
        const int ks  = rem & 1;         // 0..1  (32-ci half of c5)
        const float step = *step_w_p;
        const float inv  = 1.0f / step;

        for (int idx = t; idx < 2304; idx += 256) {
            const int co_l = idx / 72;
            const int m4   = idx - co_l * 72;
            const float4 v = *(const float4*)(
                w + (size_t)(cot * 32 + co_l) * 2880 + c5 * 576 + ks * 288 + m4 * 4);
            float* dst = &F[co_l * 289 + m4 * 4];
            dst[0] = v.x; dst[1] = v.y; dst[2] = v.z; dst[3] = v.w;
        }
        __syncthreads();

        // thread t writes bytes [t*4, t*4+4) of each p's 1024B block:
        // lane = t>>2, j0 = (t&3)*4; co_l = lane&31; ci_l = (lane>>5)*16+j0+k
        const int co_l = (t >> 2) & 31;
        const int cib  = (t >> 7) * 16 + (t & 3) * 4;
        char* dst = wq2 + (size_t)(c5 * 20 + ks * 10 + cot) * 1024 + t * 4;
#pragma unroll
        for (int p = 0; p < 9; ++p) {
            int word = 0;
#pragma unroll
            for (int k = 0; k < 4; ++k) {
                float v = F[co_l * 289 + (cib + k) * 9 + p];
                int q = (int)clampf(qround(v, step, inv), -QMAX, QMAX);
                word |= (q & 0xFF) << (8 * k);
            }
            *(int*)(dst + (size_t)p * 102400) = word;
        }
    } else if (bid < 1449) {
        // ---- halo zeroing ----
        int tid = (bid - 1124) * 256 + t;
        if (tid < 83200) {
            int b = tid / 5200;
            int r = tid - b * 5200;
            int px = r / 20;
            int pc = r - px * 20;        // piece 0..19 = (c5, ks, hi)
            int c5 = pc >> 2, q = pc & 3;
            int row, col;
            if (px < 66)       { row = 0;  col = px; }
            else if (px < 132) { row = 65; col = px - 66; }
            else { int e = px - 132; row = 1 + (e >> 1); col = (e & 1) * 65; }
            size_t off = ((size_t)(b * 66 + row)) * 21120 + c5 * 4224
                       + (q >> 1) * 2112 + col * 32 + (q & 1) * 16;
            v4i z = {0, 0, 0, 0};
            *(v4i*)&xq[off] = z;
        }
    } else {
        // ---- bias requant ----
        const float step_b = *step_b_p;
        const float xs = 1.0f / *step_x_p;
        const float ws = 1.0f / *step_w_p;
        const float shift = *shift_p;
#pragma unroll
        for (int co = t; co < 320; co += 256) {
            float b_deq = clampf(rintf(bias[co] / step_b), -QMAX, QMAX) * step_b;
            float v = ((b_deq * shift) * xs) * ws;
            bi[co] = clampf(rintf(v), -QMAX, QMAX);
        }
    }
}

// ---------------------------------------------------------------------------
// Implicit-GEMM conv — v_mfma_i32_32x32x32_i8 (round-9: ks-split layout).
// Round-4 structure preserved (grid 1280, XCD remap, dbuf B staging,
// A distance-1 dbuf, 3 waves/SIMD). 8 x 32x32x32 per p: half the MFMA
// instructions of 16x16x64, ceiling 4404 vs 3944 TOPS.
// ROUND-7/8 LESSON: XOR-keying hole-y 32B-per-col reads does NOT fix bank
// conflicts (3.7M then 11.1M). The only measured-0-conflict pattern is a
// fully contiguous 1024B region per ds_read_b128 — so the ks-split xq/LDS
// layout makes every B-read contiguous BY CONSTRUCTION (no swizzle at all).
// LDS per c5 buffer: [6 row][2 ks][66 col][2 hi][16] = 25344B.
// B-read (fixed h,ks): addr = const + l31*32 + hi*16 -> contiguous 1024B.
// ROUND-3: no ptile pairing. ROUND-5: no small-tile retile.
// ROUND-6: no distance-2 prefetch.
// ---------------------------------------------------------------------------
__global__ __launch_bounds__(256, 3) void conv_mfma_kernel(
    const char* __restrict__ xq, const char* __restrict__ wq2,
    const float* __restrict__ bi, const float* __restrict__ shift_p,
    float* __restrict__ out)
{
    __shared__ __attribute__((aligned(16))) char B_lds[2][25344];

    const int t  = threadIdx.x;
    const int id = blockIdx.x;           // 0..1279
    // id = (ptile&7) + 8*bx + 40*(ptile>>3)  -- invert:
    const int g  = id / 40;
    const int r  = id - g * 40;
    const int bx = r >> 3;               // co tile 0..4 (64 co each)
    const int ptile = (g << 3) | (r & 7);

    const int co0 = bx * 64;
    const int b  = ptile >> 4;
    const int h0 = (ptile & 15) * 4;

    const int wave = t >> 6, lane = t & 63;
    const int l31 = lane & 31, hi = lane >> 5;

    // xq row stride = 21120 B; per (row,c5): 4224 B contiguous [ks][col][hi]
    const char* xbase = xq + (size_t)(b * 66 + h0) * 21120;

    v16i acc[2][2] = {};   // [ct (32-co tile)][h (32-px half)]

    // staging: identity copy of 6 rows x 4224B (contiguous per row) per c5
    // c in [0,1584): row = c/264, rem = c%264 -> global row*21120 + rem*16
    // LDS dst linear c*16 (wave-uniform base + lane*16, as required).
    // prologue: stage c5=0 into buffer 0
    for (int c = t; c < 1584; c += 256) {
        const int row = c / 264;
        const int rem = c - row * 264;
        const char* gp = xbase + row * 21120 + rem * 16;
        gload_lds16(gp, &B_lds[0][(c - lane) * 16]);
    }
    __syncthreads();

    for (int c5 = 0; c5 < 5; ++c5) {
        // issue next stage's DMA first (other buffer; drained by the barrier
        // AFTER this c5's compute -> fully overlapped)
        if (c5 < 4) {
            char* dst = B_lds[(c5 + 1) & 1];
            for (int c = t; c < 1584; c += 256) {
                const int row = c / 264;
                const int rem = c - row * 264;
                const char* gp = xbase + row * 21120 + (c5 + 1) * 4224 + rem * 16;
                gload_lds16(gp, &dst[(c - lane) * 16]);
            }
        }

        const char* Bc = B_lds[c5 & 1];
        const char* wp = wq2 + (c5 * 20 + bx * 2) * 1024 + lane * 16;

        // A distance-1 double-buffer: [buf][ct][ks]
        v4i areg[2][2][2];
#pragma unroll
        for (int ct = 0; ct < 2; ++ct)
#pragma unroll
            for (int ks = 0; ks < 2; ++ks)
                areg[0][ct][ks] = *(const v4i*)(wp + ks * 10240 + ct * 1024);

#pragma unroll
        for (int p = 0; p < 9; ++p) {
            const int dh = p / 3, dw = p - dh * 3;
            if (p < 8) {
#pragma unroll
                for (int ct = 0; ct < 2; ++ct)
#pragma unroll
                    for (int ks = 0; ks < 2; ++ks)
                        areg[(p + 1) & 1][ct][ks] = *(const v4i*)(
                            wp + (p + 1) * 102400 + ks * 10240 + ct * 1024);
            }
            const int prow = wave + dh;
            v4i bf[2][2];  // [h2][ks]
#pragma unroll
            for (int h2 = 0; h2 < 2; ++h2) {
                const int col = h2 * 32 + l31 + dw;
                const int cbase = prow * 4224 + col * 32 + (hi << 4);
#pragma unroll
                for (int ks = 0; ks < 2; ++ks)
                    bf[h2][ks] = *(const v4i*)&Bc[cbase + ks * 2112];
            }
            __builtin_amdgcn_s_setprio(1);
#pragma unroll
            for (int ks = 0; ks < 2; ++ks)      // ks outer: acc-reuse dist 4
#pragma unroll
                for (int h2 = 0; h2 < 2; ++h2)
#pragma unroll
                    for (int ct = 0; ct < 2; ++ct)
                        acc[ct][h2] = mfma32_i8(areg[p & 1][ct][ks], bf[h2][ks],
                                                acc[ct][h2]);
            __builtin_amdgcn_s_setprio(0);
        }
        __syncthreads();
    }

    // epilogue: y_shift = clip(rint(y*shift)); out = clip(y_shift + b_int8)
    // C/D 32x32: col = lane&31 (px), row = (reg&3) + 8*(reg>>2) + 4*hi (co)
    const float shift = *shift_p;
    const int h = h0 + wave;
#pragma unroll
    for (int ct = 0; ct < 2; ++ct) {
#pragma unroll
        for (int reg = 0; reg < 16; ++reg) {
            const int row = (reg & 3) + 8 * (reg >> 2) + 4 * hi;
            const int co = co0 + ct * 32 + row;
            const float bv = bi[co];
            float* orow = out + (((size_t)(b * 320 + co) * 64) + h) * 64;
#pragma unroll
            for (int hh = 0; hh < 2; ++hh) {
                float y  = (float)acc[ct][hh][reg];
                float ys = clampf(rintf(y * shift), -QMAX, QMAX);
                orow[hh * 32 + l31] = clampf(ys + bv, -QMAX, QMAX);
            }
        }
    }
}

extern "C" void kernel_launch(void* const* d_in, const int* in_sizes, int n_in,
                              void* d_out, int out_size, void* d_ws, size_t ws_size,
                              hipStream_t stream) {
    const float* x      = (const float*)d_in[0];
    const float* w      = (const float*)d_in[1];
    const float* bias   = (const float*)d_in[2];
    const float* step_x = (const float*)d_in[3];
    const float* step_w = (const float*)d_in[4];
    const float* step_b = (const float*)d_in[5];
    const float* shift  = (const float*)d_in[6];
    float* out = (float*)d_out;

    char*  xq  = (char*)d_ws;
    char*  wq2 = xq + XQ_BYTES;
    float* bi  = (float*)(wq2 + WQ_BYTES);

    fused_prep_kernel<<<1450, 256, 0, stream>>>(x, w, bias, step_x, step_w,
                                                step_b, shift, xq, wq2, bi);
    conv_mfma_kernel<<<1280, 256, 0, stream>>>(xq, wq2, bi, shift, out);
}

// Round 10
// 211.950 us; speedup vs baseline: 1.0590x; 1.0496x over previous
//
#include <hip/hip_runtime.h>

typedef int v4i __attribute__((ext_vector_type(4)));

#define QMAX 127.0f

// ---- workspace layout ----
// xq  : int8 padded, swizzled [16][66][66 px][5 c5][4 slots][16]
//       slot s of (col,c5) holds logical ci-chunk s ^ ((col>>1)&3)
// wq2 : int8 fragment-order [9][5][20cog][64lane][16]
// bi  : float [320]
#define XQ_BYTES 22302720
#define WQ_BYTES 921600

__device__ __forceinline__ float clampf(float v, float lo, float hi) {
    return fminf(fmaxf(v, lo), hi);
}

// Bit-exact fast round(v/step): reciprocal multiply, exact-division fallback
// only near half-integer boundaries (trigger ~7e-4; 50x error margin).
__device__ __forceinline__ float qround(float v, float step, float inv) {
    float t = v * inv;
    float r = rintf(t);
    float d = fabsf(t - r);
    if (fabsf(d - 0.5f) < fabsf(t) * 1e-5f + 1e-5f)
        r = rintf(v / step);
    return r;
}

__device__ __forceinline__ void gload_lds16(const char* g, char* l) {
    __builtin_amdgcn_global_load_lds(
        (const __attribute__((address_space(1))) void*)g,
        (__attribute__((address_space(3))) void*)l, 16, 0, 0);
}

__device__ __forceinline__ v4i mfma_i8(v4i a, v4i b, v4i c) {
    return __builtin_amdgcn_mfma_i32_16x16x64_i8(a, b, c, 0, 0, 0);
}

// ---------------------------------------------------------------------------
// Fused producer kernel (round-4 proven):
//   blocks [0,1024)    : x quantize (block = (h,b)), long pole -> first
//   blocks [1024,1124) : wq2 quantize, LDS-staged coalesced transform
//   blocks [1124,1449) : xq halo zeroing
//   block  1449        : bias requant
// ---------------------------------------------------------------------------
__global__ __launch_bounds__(256) void fused_prep_kernel(
    const float* __restrict__ x, const float* __restrict__ w,
    const float* __restrict__ bias,
    const float* __restrict__ step_x_p, const float* __restrict__ step_w_p,
    const float* __restrict__ step_b_p, const float* __restrict__ shift_p,
    char* __restrict__ xq, char* __restrict__ wq2, float* __restrict__ bi)
{
    // x-quant uses F as [64][65]; wq uses F as [16][577] (36,928 B)
    __shared__ float F[16 * 577];
    const int bid = blockIdx.x;
    const int t = threadIdx.x;

    if (bid < 1024) {
        // ---- x quantize: one block per (h,b); writes row h+1 interior ----
        const int h = bid & 63;
        const int b = bid >> 6;
        const float step = *step_x_p;
        const float inv  = 1.0f / step;
        const int wcol = t >> 2;       // output col-1 (0..63)
        const int cg   = t & 3;        // logical 16-ci chunk within c5
        v4i vals[5];

        for (int c5 = 0; c5 < 5; ++c5) {
            {
                const int r = t >> 4, c = (t & 15) * 4;
                const float* src = x + (((size_t)(b * 320 + c5 * 64) * 64 + h) * 64);
#pragma unroll
                for (int i = 0; i < 4; ++i) {
                    const int row = r + i * 16;
                    *(float4*)&F[row * 65 + c] =
                        *(const float4*)(src + (size_t)row * 4096 + c);
                }
            }
            __syncthreads();
            int dws[4];
#pragma unroll
            for (int j = 0; j < 4; ++j) {
                int word = 0;
#pragma unroll
                for (int k = 0; k < 4; ++k) {
                    float v = F[(cg * 16 + j * 4 + k) * 65 + wcol];
                    int xi = (int)clampf(qround(v, step, inv), -QMAX, QMAX);
                    word |= (xi & 0xFF) << (8 * k);
                }
                dws[j] = word;
            }
            vals[c5] = (v4i){dws[0], dws[1], dws[2], dws[3]};
            __syncthreads();
        }

        const int col = wcol + 1;
        const int key = (col >> 1) & 3;
        char* base = xq + ((size_t)(b * 66 + (h + 1)) * 66 + col) * 320;
#pragma unroll
        for (int c5 = 0; c5 < 5; ++c5)
            *(v4i*)(base + c5 * 64 + (((cg ^ key)) << 4)) = vals[c5];

    } else if (bid < 1124) {
        // ---- weight quantize, coalesced: block = (cog, c5) ----
        const int blk = bid - 1024;      // 0..99
        const int cog = blk / 5;         // 0..19
        const int c5  = blk - cog * 5;   // 0..4
        const int co0 = cog * 16;
        const float step = *step_w_p;
        const float inv  = 1.0f / step;

        for (int idx = t; idx < 2304; idx += 256) {
            const int co_l = idx / 144;
            const int m4   = idx - co_l * 144;
            const float4 v = *(const float4*)(
                w + (size_t)(co0 + co_l) * 2880 + c5 * 576 + m4 * 4);
            float* dst = &F[co_l * 577 + m4 * 4];
            dst[0] = v.x; dst[1] = v.y; dst[2] = v.z; dst[3] = v.w;
        }
        __syncthreads();

        const int co_l = (t >> 2) & 15;            // co within cog
        const int cib  = (t >> 6) * 16 + (t & 3) * 4;  // ci_local base
        char* dst = wq2 + (size_t)(c5 * 20 + cog) * 1024 + t * 4;
#pragma unroll
        for (int p = 0; p < 9; ++p) {
            int word = 0;
#pragma unroll
            for (int k = 0; k < 4; ++k) {
                float v = F[co_l * 577 + (cib + k) * 9 + p];
                int q = (int)clampf(qround(v, step, inv), -QMAX, QMAX);
                word |= (q & 0xFF) << (8 * k);
            }
            *(int*)(dst + (size_t)p * 102400) = word;
        }
    } else if (bid < 1449) {
        // ---- halo zeroing ----
        int tid = (bid - 1124) * 256 + t;
        if (tid < 83200) {
            int b = tid / 5200;
            int r = tid - b * 5200;
            int px = r / 20;
            int ck = (r - px * 20) * 16;
            int row, col;
            if (px < 66)       { row = 0;  col = px; }
            else if (px < 132) { row = 65; col = px - 66; }
            else { int e = px - 132; row = 1 + (e >> 1); col = (e & 1) * 65; }
            size_t off = ((size_t)(b * 66 + row) * 66 + col) * 320 + ck;
            v4i z = {0, 0, 0, 0};
            *(v4i*)&xq[off] = z;
        }
    } else {
        // ---- bias requant ----
        const float step_b = *step_b_p;
        const float xs = 1.0f / *step_x_p;
        const float ws = 1.0f / *step_w_p;
        const float shift = *shift_p;
#pragma unroll
        for (int co = t; co < 320; co += 256) {
            float b_deq = clampf(rintf(bias[co] / step_b), -QMAX, QMAX) * step_b;
            float v = ((b_deq * shift) * xs) * ws;
            bi[co] = clampf(rintf(v), -QMAX, QMAX);
        }
    }
}

// ---------------------------------------------------------------------------
// Implicit-GEMM conv, v_mfma_i32_16x16x64_i8 — round-4 kernel, the session's
// empirical optimum (61.0-62.2us, reproduced 3x). Restored verbatim.
// Block = 4 waves; wave tile 64co x 64px (1 output row); acc 64 AGPR;
// launch_bounds(256,3) -> 3 waves/SIMD. Grid 1280, XCD remap id%8=(ptile&7)
// -> 5 co-tiles of a ptile adjacent on one XCD (FETCH 117->25.7MB, R1 win).
// SESSION LEDGER (measured, do not retry):
//  R3: ptile pairing (640 blk)     -> 76.7us (TLP loss, L2 WS doubled)
//  R5: 80co x 32px retile (4w/SIMD)-> 82.5us (phase cover halved, A L2 2x)
//  R6: A prefetch distance 2       -> 69.8us (compiler sched already good)
//  R7-R9: 32x32x32 MFMA, 3 layouts -> 73.5-81.4us (B-frag 32colx2chunk read
//         bank-conflicts +4..+12cy/read under every swizzle tried; only the
//         16colx4chunk read with key=(col>>1)&3 measures 0 conflicts)
// Residual gap to the 30.6us MFMA floor is operand-feed + barrier
// rendezvous; five structural attempts to shrink it all regressed.
// ---------------------------------------------------------------------------
__global__ __launch_bounds__(256, 3) void conv_mfma_kernel(
    const char* __restrict__ xq, const char* __restrict__ wq2,
    const float* __restrict__ bi, const float* __restrict__ shift_p,
    float* __restrict__ out)
{
    __shared__ __attribute__((aligned(16))) char B_lds[2][25344]; // 6 rows x 66 x 64

    const int t  = threadIdx.x;
    const int id = blockIdx.x;           // 0..1279
    // id = (ptile&7) + 8*bx + 40*(ptile>>3)  -- invert:
    const int g  = id / 40;
    const int r  = id - g * 40;
    const int bx = r >> 3;               // co tile 0..4
    const int ptile = (g << 3) | (r & 7);

    const int co0 = bx * 64;
    const int b  = ptile >> 4;
    const int h0 = (ptile & 15) * 4;

    const int wave = t >> 6, lane = t & 63;
    const int quad = lane >> 4, l15 = lane & 15;

    const char* xbase = xq + ((size_t)(b * 66 + h0) * 66) * 320;

    v4i acc[4][4] = {};

    // prologue: stage c5=0 into buffer 0
    for (int c = t; c < 1584; c += 256) {
        const char* gp = xbase + (c >> 2) * 320 + ((c & 3) << 4);
        gload_lds16(gp, &B_lds[0][(c - lane) * 16]);
    }
    __syncthreads();

    for (int c5 = 0; c5 < 5; ++c5) {
        // issue next stage's DMA first (lands in the other buffer; drained by
        // the barrier AFTER this c5's compute -> fully overlapped)
        if (c5 < 4) {
            const int ci0 = (c5 + 1) * 64;
            char* dst = B_lds[(c5 + 1) & 1];
            for (int c = t; c < 1584; c += 256) {
                const char* gp = xbase + (c >> 2) * 320 + ci0 + ((c & 3) << 4);
                gload_lds16(gp, &dst[(c - lane) * 16]);
            }
        }

        const char* Bc = B_lds[c5 & 1];
        const char* wp = wq2 + (c5 * 20 + bx * 4) * 1024 + lane * 16;

        // A double-buffer: prefetch p+1's 4 fragments while p's MFMAs run.
        v4i areg[2][4];
#pragma unroll
        for (int cs = 0; cs < 4; ++cs)
            areg[0][cs] = *(const v4i*)(wp + 0 * 102400 + cs * 1024);

#pragma unroll
        for (int p = 0; p < 9; ++p) {
            const int dh = p / 3, dw = p - dh * 3;
            if (p < 8) {
#pragma unroll
                for (int cs = 0; cs < 4; ++cs)
                    areg[(p + 1) & 1][cs] =
                        *(const v4i*)(wp + (p + 1) * 102400 + cs * 1024);
            }
            const int prow = wave + dh;
            auto bread = [&](int i) -> v4i {
                const int col = i * 16 + l15 + dw;
                const int key = (col >> 1) & 3;
                return *(const v4i*)&Bc[(prow * 66 + col) * 64 +
                                        ((quad ^ key) << 4)];
            };
            v4i bf = bread(0);
#pragma unroll
            for (int i = 0; i < 4; ++i) {
                v4i bcur = bf;
                if (i < 3) bf = bread(i + 1);
                __builtin_amdgcn_s_setprio(1);
#pragma unroll
                for (int cs = 0; cs < 4; ++cs)
                    acc[cs][i] = mfma_i8(areg[p & 1][cs], bcur, acc[cs][i]);
                __builtin_amdgcn_s_setprio(0);
            }
        }
        __syncthreads();
    }

    // epilogue: y_shift = clip(rint(y*shift)); out = clip(y_shift + b_int8)
    const float shift = *shift_p;
    const int h = h0 + wave;
#pragma unroll
    for (int cs = 0; cs < 4; ++cs) {
#pragma unroll
        for (int reg = 0; reg < 4; ++reg) {
            const int co = co0 + cs * 16 + quad * 4 + reg;
            const float bv = bi[co];
            float* orow = out + (((size_t)(b * 320 + co) * 64) + h) * 64;
#pragma unroll
            for (int i = 0; i < 4; ++i) {
                float y  = (float)acc[cs][i][reg];
                float ys = clampf(rintf(y * shift), -QMAX, QMAX);
                orow[i * 16 + l15] = clampf(ys + bv, -QMAX, QMAX);
            }
        }
    }
}

extern "C" void kernel_launch(void* const* d_in, const int* in_sizes, int n_in,
                              void* d_out, int out_size, void* d_ws, size_t ws_size,
                              hipStream_t stream) {
    const float* x      = (const float*)d_in[0];
    const float* w      = (const float*)d_in[1];
    const float* bias   = (const float*)d_in[2];
    const float* step_x = (const float*)d_in[3];
    const float* step_w = (const float*)d_in[4];
    const float* step_b = (const float*)d_in[5];
    const float* shift  = (const float*)d_in[6];
    float* out = (float*)d_out;

    char*  xq  = (char*)d_ws;
    char*  wq2 = xq + XQ_BYTES;
    float* bi  = (float*)(wq2 + WQ_BYTES);

    fused_prep_kernel<<<1450, 256, 0, stream>>>(x, w, bias, step_x, step_w,
                                                step_b, shift, xq, wq2, bi);
    conv_mfma_kernel<<<1280, 256, 0, stream>>>(xq, wq2, bi, shift, out);
}